// Round 7
// baseline (75.885 us; speedup 1.0000x reference)
//
#include <hip/hip_runtime.h>

// Problem constants (from reference): x:(B,G) f32, WQ/WK/WV:(H,G,1) f32, W0:(H,) f32
constexpr int B    = 16;
constexpr int G    = 1708;
constexpr int H    = 5;
constexpr int M1   = 17;            // moments m = 0..16 (degree-16 exp series)
constexpr int TPB  = 320;           // 5 waves: wave w owns head w's moment scan
constexpr int ROWS = 128;           // output rows per block (phase 2)
constexpr int TILES = (G + ROWS - 1) / ROWS;   // 14

#define LOG2E 1.4426950408889634f

// Rank-1 score structure: scores[b,i,j] = q_i * k_j, so
//   D(q) = sum_j exp(q k_j)      = sum_m (S_m/m!) q^m,  S_m = sum_j k_j^m
//   N(q) = sum_j v_j exp(q k_j)  = sum_m (T_m/m!) q^m,  T_m = sum_j v_j k_j^m
// out[b,i] = sum_h W0[h] * (N(q_i) - exp(q_i k_i) v_i) / D(q_i)
// |q k| <= ~1.4 => truncation error < 1.4^17/17! ~ 4e-13: exact at fp32.
//
// SINGLE fused node. Each block recomputes the moments for its b (14x
// redundant — negligible FLOPs). Key lesson from R5's failed fusion: the
// shfl butterfly is DS-pipe depth shared per-CU; all-waves×all-heads was
// 4080 DS ops/block. Here ONE WAVE PER HEAD: 5×~140 DS ops/block (8x less).

__device__ __forceinline__ float fast_exp(float x) {
#if __has_builtin(__builtin_amdgcn_exp2f)
    return __builtin_amdgcn_exp2f(x * LOG2E);
#else
    return __expf(x);
#endif
}

__constant__ float INVFACT[M1] = {
    (float)(1.0),                    (float)(1.0),
    (float)(1.0 / 2.0),              (float)(1.0 / 6.0),
    (float)(1.0 / 24.0),             (float)(1.0 / 120.0),
    (float)(1.0 / 720.0),            (float)(1.0 / 5040.0),
    (float)(1.0 / 40320.0),          (float)(1.0 / 362880.0),
    (float)(1.0 / 3628800.0),        (float)(1.0 / 39916800.0),
    (float)(1.0 / 479001600.0),      (float)(1.0 / 6227020800.0),
    (float)(1.0 / 87178291200.0),    (float)(1.0 / 1307674368000.0),
    (float)(1.0 / 20922789888000.0)
};

__global__ __launch_bounds__(TPB)
void fused_kernel(const float* __restrict__ x,
                  const float* __restrict__ WQ,
                  const float* __restrict__ WK,
                  const float* __restrict__ WV,
                  const float* __restrict__ W0,
                  float* __restrict__ out)
{
    __shared__ float red[H][8][2 * M1];   // 5.3 KB butterfly partials
    __shared__ float mom[H * 2 * M1];     // 680 B final scaled moments

    const int b    = blockIdx.y;
    const int tid  = threadIdx.x;
    const int lane = tid & 63;
    const int wave = tid >> 6;            // == head index for phase 1

    const float* __restrict__ xb = x  + b * G;
    const float* __restrict__ wk = WK + wave * G;
    const float* __restrict__ wv = WV + wave * G;

    // ---- Phase 1: wave `wave` scans ALL j for head `wave` ----
    float S[M1], T[M1];
#pragma unroll
    for (int m = 0; m < M1; ++m) { S[m] = 0.f; T[m] = 0.f; }

    for (int t = lane; t < G; t += 64) {      // 27 coalesced iterations
        const float xj = xb[t];
        const float k  = xj * wk[t];
        const float v  = xj * wv[t];
        const float k2 = k * k;
        const float k4 = k2 * k2;
        float p0 = 1.f, p1 = k, p2 = k2, p3 = k2 * k;   // 4 chains, step k^4
#pragma unroll
        for (int gblk = 0; gblk < 4; ++gblk) {
            const int base = gblk * 4;
            S[base + 0] += p0; T[base + 0] = fmaf(v, p0, T[base + 0]); p0 *= k4;
            S[base + 1] += p1; T[base + 1] = fmaf(v, p1, T[base + 1]); p1 *= k4;
            S[base + 2] += p2; T[base + 2] = fmaf(v, p2, T[base + 2]); p2 *= k4;
            S[base + 3] += p3; T[base + 3] = fmaf(v, p3, T[base + 3]); p3 *= k4;
        }
        S[16] += p0; T[16] = fmaf(v, p0, T[16]);         // p0 == k^16
    }

    // 3-step xor butterfly: lane l ends with the sum over lanes sharing l&7.
#pragma unroll
    for (int m = 0; m < M1; ++m) {
#pragma unroll
        for (int off = 8; off <= 32; off <<= 1) {
            S[m] += __shfl_xor(S[m], off, 64);
            T[m] += __shfl_xor(T[m], off, 64);
        }
    }
    if (lane < 8) {
#pragma unroll
        for (int m = 0; m < M1; ++m) {
            red[wave][lane][m]      = S[m];
            red[wave][lane][M1 + m] = T[m];
        }
    }
    __syncthreads();

    // ---- Phase 1b: 170 threads fold the 8 rows into mom[] ----
    if (tid < H * 2 * M1) {
        const int h = tid / (2 * M1);
        const int c = tid % (2 * M1);
        float s0 = 0.f, s1 = 0.f;
#pragma unroll
        for (int r = 0; r < 8; r += 2) {
            s0 += red[h][r + 0][c];
            s1 += red[h][r + 1][c];
        }
        const int m = (c < M1) ? c : (c - M1);
        mom[tid] = (s0 + s1) * INVFACT[m];
    }
    __syncthreads();

    // ---- Phase 2: 128 rows per block, Horner per head + diagonal fix ----
    const int i = blockIdx.x * ROWS + tid;
    if (tid < ROWS && i < G) {
        const float xi = xb[i];
        float acc = 0.f;
#pragma unroll
        for (int h = 0; h < H; ++h) {
            const float* __restrict__ mp = mom + h * (2 * M1);  // LDS broadcasts
            const float q = xi * WQ[h * G + i];

            float D = mp[M1 - 1];
            float N = mp[2 * M1 - 1];
#pragma unroll
            for (int m = M1 - 2; m >= 0; --m) {
                D = fmaf(D, q, mp[m]);
                N = fmaf(N, q, mp[M1 + m]);
            }

            const float k   = xi * WK[h * G + i];
            const float v   = xi * WV[h * G + i];
            const float eii = fast_exp(q * k);   // diagonal removed post-softmax
            acc = fmaf(W0[h], (N - eii * v) / D, acc);
        }
        out[b * G + i] = acc;
    }
}

extern "C" void kernel_launch(void* const* d_in, const int* in_sizes, int n_in,
                              void* d_out, int out_size, void* d_ws, size_t ws_size,
                              hipStream_t stream) {
    const float* x  = (const float*)d_in[0];
    const float* WQ = (const float*)d_in[1];
    const float* WK = (const float*)d_in[2];
    const float* WV = (const float*)d_in[3];
    const float* W0 = (const float*)d_in[4];
    float* out = (float*)d_out;

    dim3 grid(TILES, B);   // (14, 16) = 224 blocks ~ 1 per CU — ONE graph node
    fused_kernel<<<grid, TPB, 0, stream>>>(x, WQ, WK, WV, W0, out);
}

// Round 8
// 67.257 us; speedup vs baseline: 1.1283x; 1.1283x over previous
//
#include <hip/hip_runtime.h>

// Problem constants (from reference): x:(B,G) f32, WQ/WK/WV:(H,G,1) f32, W0:(H,) f32
constexpr int B = 16;
constexpr int G = 1708;
constexpr int H = 5;
constexpr int M1 = 17;          // moments m = 0..16 (degree-16 truncation of exp series)
constexpr int JS = 4;           // j-slices per (b,h) in the moments kernel
constexpr int JPS = G / JS;     // 427 (1708 = 4*427 exact)
constexpr int TPB1 = 256;       // moments kernel block
constexpr int TPB2 = 64;        // eval kernel block (1 wave)

#define LOG2E 1.4426950408889634f

// Rank-1 score structure: scores[b,i,j] = q_i * k_j, so
//   D(q) = sum_j exp(q k_j)      = sum_m (S_m/m!) q^m,  S_m = sum_j k_j^m
//   N(q) = sum_j v_j exp(q k_j)  = sum_m (T_m/m!) q^m,  T_m = sum_j v_j k_j^m
// out[b,i] = sum_h W0[h] * (N(q_i) - exp(q_i k_i) v_i) / D(q_i)
// |q k| <= ~1.4  =>  truncation error < 1.4^17/17! ~ 4e-13: exact at fp32.
// g_mom in d_ws: [B*H][JS][2*M1] per-slice partials (scaled by 1/m!), written
// disjointly (no atomics -> no memset node); eval sums the 4 slices itself.
//
// STRUCTURE NOTE (R5/R7 post-mortems): do NOT fuse into one node. Fusion
// forces every block to recompute all H heads' moments -> 27-deep serial
// load-use chains with 34 live accumulators (no VGPR room to pipeline)
// ~= +8.5 us measured, twice. Two shallow nodes (~2 j/thread) win.

__device__ __forceinline__ float fast_exp(float x) {
#if __has_builtin(__builtin_amdgcn_exp2f)
    return __builtin_amdgcn_exp2f(x * LOG2E);
#else
    return __expf(x);
#endif
}

__constant__ float INVFACT[M1] = {
    (float)(1.0),                    (float)(1.0),
    (float)(1.0 / 2.0),              (float)(1.0 / 6.0),
    (float)(1.0 / 24.0),             (float)(1.0 / 120.0),
    (float)(1.0 / 720.0),            (float)(1.0 / 5040.0),
    (float)(1.0 / 40320.0),          (float)(1.0 / 362880.0),
    (float)(1.0 / 3628800.0),        (float)(1.0 / 39916800.0),
    (float)(1.0 / 479001600.0),      (float)(1.0 / 6227020800.0),
    (float)(1.0 / 87178291200.0),    (float)(1.0 / 1307674368000.0),
    (float)(1.0 / 20922789888000.0)
};

// Kernel 1: grid = B*H*JS blocks; block reduces one j-slice of one (b,h) and
// STORES the 34 scaled partial moments to its own g_mom slot (disjoint).
__global__ __launch_bounds__(TPB1)
void moments_kernel(const float* __restrict__ x,
                    const float* __restrict__ WK,
                    const float* __restrict__ WV,
                    float* __restrict__ g_mom)
{
    const int slice = blockIdx.x % JS;
    const int h     = (blockIdx.x / JS) % H;
    const int b     = blockIdx.x / (JS * H);
    const int j0    = slice * JPS;

    const float* __restrict__ xb = x  + b * G;
    const float* __restrict__ wk = WK + h * G;
    const float* __restrict__ wv = WV + h * G;

    float S[M1], T[M1];
#pragma unroll
    for (int m = 0; m < M1; ++m) { S[m] = 0.f; T[m] = 0.f; }

    // <=2 j's per thread; 4 parallel power chains (step k^4) keep the dep
    // chain ~4 muls deep instead of 16.
    for (int t = threadIdx.x; t < JPS; t += TPB1) {
        const int j   = j0 + t;
        const float xj = xb[j];
        const float k  = xj * wk[j];
        const float v  = xj * wv[j];
        const float k2 = k * k;
        const float k4 = k2 * k2;
        float p0 = 1.f, p1 = k, p2 = k2, p3 = k2 * k;
#pragma unroll
        for (int gblk = 0; gblk < 4; ++gblk) {
            const int base = gblk * 4;
            S[base + 0] += p0; T[base + 0] = fmaf(v, p0, T[base + 0]); p0 *= k4;
            S[base + 1] += p1; T[base + 1] = fmaf(v, p1, T[base + 1]); p1 *= k4;
            S[base + 2] += p2; T[base + 2] = fmaf(v, p2, T[base + 2]); p2 *= k4;
            S[base + 3] += p3; T[base + 3] = fmaf(v, p3, T[base + 3]); p3 *= k4;
        }
        S[16] += p0; T[16] = fmaf(v, p0, T[16]);   // p0 is now k^16
    }

    // 3-step butterfly: lane l ends with the sum over lanes j with j&7 == l&7.
#pragma unroll
    for (int m = 0; m < M1; ++m) {
#pragma unroll
        for (int off = 8; off <= 32; off <<= 1) {
            S[m] += __shfl_xor(S[m], off, 64);
            T[m] += __shfl_xor(T[m], off, 64);
        }
    }

    __shared__ float red[4 * 8][2 * M1];   // 32 rows x 34 scalars = 4.25 KB
    const int wave = threadIdx.x >> 6;
    const int lane = threadIdx.x & 63;
    if (lane < 8) {
        const int row = wave * 8 + lane;
#pragma unroll
        for (int m = 0; m < M1; ++m) {
            red[row][m]      = S[m];
            red[row][M1 + m] = T[m];
        }
    }
    __syncthreads();

    if (threadIdx.x < 2 * M1) {
        const int m = threadIdx.x % M1;
        float s0 = 0.f, s1 = 0.f, s2 = 0.f, s3 = 0.f;
#pragma unroll
        for (int r = 0; r < 32; r += 4) {
            s0 += red[r + 0][threadIdx.x];
            s1 += red[r + 1][threadIdx.x];
            s2 += red[r + 2][threadIdx.x];
            s3 += red[r + 3][threadIdx.x];
        }
        const float s = ((s0 + s1) + (s2 + s3)) * INVFACT[m];
        g_mom[((b * H + h) * JS + slice) * (2 * M1) + threadIdx.x] = s;
    }
}

// Kernel 2: one wave per 64 rows. Stage + slice-sum the 170 moments into LDS,
// then degree-16 Horner per head + diagonal fix.
__global__ __launch_bounds__(TPB2)
void eval_kernel(const float* __restrict__ x,
                 const float* __restrict__ WQ,
                 const float* __restrict__ WK,
                 const float* __restrict__ WV,
                 const float* __restrict__ W0,
                 const float* __restrict__ g_mom,
                 float* __restrict__ out)
{
    __shared__ float mom[H * 2 * M1];      // 170 floats = 680 B

    const int b = blockIdx.y;
    const int i = blockIdx.x * TPB2 + threadIdx.x;

    // fold the 4 slice partials: 3 columns per thread, coalesced-ish loads
    for (int c = threadIdx.x; c < H * 2 * M1; c += TPB2) {
        const int h  = c / (2 * M1);
        const int cc = c % (2 * M1);
        const float* __restrict__ p = g_mom + ((b * H + h) * JS) * (2 * M1) + cc;
        mom[c] = (p[0] + p[2 * M1]) + (p[2 * (2 * M1)] + p[3 * (2 * M1)]);
    }
    __syncthreads();

    if (i >= G) return;

    const float xi = x[b * G + i];
    float acc = 0.f;

#pragma unroll
    for (int h = 0; h < H; ++h) {
        const float* __restrict__ mp = mom + h * (2 * M1);   // LDS broadcast reads
        const float q = xi * WQ[h * G + i];

        float D = mp[M1 - 1];
        float N = mp[2 * M1 - 1];
#pragma unroll
        for (int m = M1 - 2; m >= 0; --m) {
            D = fmaf(D, q, mp[m]);
            N = fmaf(N, q, mp[M1 + m]);
        }

        const float k   = xi * WK[h * G + i];
        const float v   = xi * WV[h * G + i];
        const float eii = fast_exp(q * k);       // diagonal removed post-softmax
        acc = fmaf(W0[h], (N - eii * v) / D, acc);
    }
    out[b * G + i] = acc;
}

extern "C" void kernel_launch(void* const* d_in, const int* in_sizes, int n_in,
                              void* d_out, int out_size, void* d_ws, size_t ws_size,
                              hipStream_t stream) {
    const float* x  = (const float*)d_in[0];
    const float* WQ = (const float*)d_in[1];
    const float* WK = (const float*)d_in[2];
    const float* WV = (const float*)d_in[3];
    const float* W0 = (const float*)d_in[4];
    float* out   = (float*)d_out;
    float* g_mom = (float*)d_ws;            // B*H*JS*2*M1 floats = 43.5 KB

    moments_kernel<<<B * H * JS, TPB1, 0, stream>>>(x, WK, WV, g_mom);

    dim3 grid2((G + TPB2 - 1) / TPB2, B);   // (27, 16), one wave per block
    eval_kernel<<<grid2, TPB2, 0, stream>>>(x, WQ, WK, WV, W0, g_mom, out);
}